// Round 1
// baseline (196.073 us; speedup 1.0000x reference)
//
#include <hip/hip_runtime.h>

#define C 2
#define H 200
#define W 200
#define NN 200

__global__ __launch_bounds__(256) void crop_split_kernel(
    const float* __restrict__ data,
    const float* __restrict__ rois,
    float* __restrict__ out)
{
    const int n = threadIdx.x;              // 0..255, active for n < NN
    const int x = blockIdx.x;               // 0..W-1
    const int y = blockIdx.y;               // 0..H-1
    if (n >= NN) return;

    // rois[n] = {x1, y1, x2, y2}
    const float4 r = reinterpret_cast<const float4*>(rois)[n];
    const float x1 = r.x, y1 = r.y, x2 = r.z, y2 = r.w;

    const float fx = (float)x;
    const float fy = (float)y;

    const bool inside = (fx >= x1) & (fx <= x2) & (fy >= y1) & (fy <= y2);

    // Match numpy float32 exactly: 2*(x-x1) is an exact pow2 scale,
    // one IEEE division, floorf, clamp to [0, C-1].
    const float cw  = fmaxf(x2 - x1, 1.0f);
    const float chh = fmaxf(y2 - y1, 1.0f);
    const float tx = (2.0f * (fx - x1)) / cw;
    const float ty = (2.0f * (fy - y1)) / chh;
    const int cx = (int)fminf(fmaxf(floorf(tx), 0.0f), (float)(C - 1));
    const int cy = (int)fminf(fmaxf(floorf(ty), 0.0f), (float)(C - 1));
    const int cell = cy * C + cx;

    const long long pix = ((long long)y * W + x) * NN + n;
    float v = 0.0f;
    if (inside) {
        v = data[(long long)cell * (H * (long long)W * NN) + pix];
    }
    out[pix] = v;
}

extern "C" void kernel_launch(void* const* d_in, const int* in_sizes, int n_in,
                              void* d_out, int out_size, void* d_ws, size_t ws_size,
                              hipStream_t stream) {
    const float* data = (const float*)d_in[0];   // (4, 200, 200, 200) f32
    const float* rois = (const float*)d_in[1];   // (200, 4) f32
    float* out = (float*)d_out;                  // (200, 200, 200) f32

    dim3 grid(W, H, 1);
    dim3 block(256, 1, 1);
    crop_split_kernel<<<grid, block, 0, stream>>>(data, rois, out);
}

// Round 2
// 181.382 us; speedup vs baseline: 1.0810x; 1.0810x over previous
//
#include <hip/hip_runtime.h>

#define C 2
#define H 200
#define W 200
#define NN 200
#define N4 (NN / 4)            // 50 float4 per pixel-row of n
#define TOTAL4 (H * W * N4)    // 2,000,000 float4 outputs
#define PLANE (H * W * NN)     // elements per data plane

__global__ __launch_bounds__(256) void crop_split_kernel(
    const float* __restrict__ data,
    const float4* __restrict__ rois4,   // 200 x {x1,y1,x2,y2}
    float4* __restrict__ out)
{
    const int j = blockIdx.x * 256 + threadIdx.x;
    if (j >= TOTAL4) return;

    const int n4  = j % N4;        // which float4 along n
    const int pix = j / N4;        // y*W + x
    const int x   = pix % W;
    const int y   = pix / W;
    const float fx = (float)x;
    const float fy = (float)y;
    const int pbase = pix * NN + n4 * 4;

    float v[4];
#pragma unroll
    for (int k = 0; k < 4; ++k) {
        const float4 r = rois4[n4 * 4 + k];   // roi for n = 4*n4 + k
        const bool inside = (fx >= r.x) & (fx <= r.z) & (fy >= r.y) & (fy <= r.w);
        float val = 0.0f;
        if (inside) {
            // bit-exact vs numpy float32: exact pow2 scale, one IEEE div,
            // floorf, clamp to [0, C-1]
            const float cw = fmaxf(r.z - r.x, 1.0f);
            const float ch = fmaxf(r.w - r.y, 1.0f);
            const float tx = (2.0f * (fx - r.x)) / cw;
            const float ty = (2.0f * (fy - r.y)) / ch;
            const int cx = (int)fminf(fmaxf(floorf(tx), 0.0f), (float)(C - 1));
            const int cy = (int)fminf(fmaxf(floorf(ty), 0.0f), (float)(C - 1));
            const int cell = cy * C + cx;
            val = data[cell * PLANE + pbase + k];
        }
        v[k] = val;
    }
    out[j] = make_float4(v[0], v[1], v[2], v[3]);
}

extern "C" void kernel_launch(void* const* d_in, const int* in_sizes, int n_in,
                              void* d_out, int out_size, void* d_ws, size_t ws_size,
                              hipStream_t stream) {
    const float* data  = (const float*)d_in[0];          // (4,200,200,200) f32
    const float4* rois = (const float4*)d_in[1];         // (200,4) f32
    float4* out = (float4*)d_out;                        // (200,200,200) f32 as float4

    const int blocks = (TOTAL4 + 255) / 256;             // 7813
    crop_split_kernel<<<blocks, 256, 0, stream>>>(data, rois, out);
}